// Round 8
// baseline (840.498 us; speedup 1.0000x reference)
//
#include <hip/hip_runtime.h>
#include <hip/hip_bf16.h>
#include <stdint.h>

// ---------------------------------------------------------------------------
// TopoPool via leveled-DAG DP (no pair frontier):
//   z = x@W.T + b ; seg-softmax elev ; peaks (no higher in-neighbor) ;
//   level[v] = BFS depth from peaks along descending edges (per-batch) ;
//   M[u] = max(x[u], max_{u->w desc, level[w]=level[u]+1} M[w])  (bottom-up) ;
//   max_x[c] = M[peak_c] ; max_elev[c] = elev[peak_c] ;
//   pooled = M[peak] * seg-softmax(elev[peak]).
// R7: k_dp half-wave (32-lane) per node with uint4 M loads, grid 2048 @
//     __launch_bounds__(256,8) (max occupancy); BFS early-exit at true depth.
// ---------------------------------------------------------------------------

#define LINF 0x3FFFFFFF
#define MAXL 60
#define LSPLIT 10

__device__ __forceinline__ unsigned encf(float f) {
  unsigned u = __float_as_uint(f);
  return (u & 0x80000000u) ? ~u : (u | 0x80000000u);
}
__device__ __forceinline__ float decf(unsigned u) {
  unsigned v = (u & 0x80000000u) ? (u & 0x7fffffffu) : ~u;
  return __uint_as_float(v);
}
__device__ __forceinline__ float bf2f(unsigned h) {
  return __uint_as_float(h << 16);
}
__device__ __forceinline__ unsigned f2bf(float f) {
  unsigned u = __float_as_uint(f);
  return (u + 0x7FFFu + ((u >> 16) & 1u)) >> 16;   // RNE
}

// wave-per-node dot(x[v], W) + b; per-block LDS batch max -> global encoded max
__global__ void k_z(const float* __restrict__ x, const float* __restrict__ W,
                    const float* __restrict__ b, const int* __restrict__ batch,
                    float* __restrict__ z, unsigned* __restrict__ bmax_enc,
                    int N, int C) {
  __shared__ unsigned smax[1024];
  for (int i = threadIdx.x; i < 1024; i += blockDim.x) smax[i] = 0u;
  __syncthreads();
  int lane = threadIdx.x & 63;
  int wid = threadIdx.x >> 6;
  int wavesPerBlock = blockDim.x >> 6;
  int gw = blockIdx.x * wavesPerBlock + wid;
  int nw = gridDim.x * wavesPerBlock;
  float b0 = b[0];
  for (int v = gw; v < N; v += nw) {
    const float* xr = x + (size_t)v * C;
    float acc = 0.f;
    for (int f = lane * 4; f < C; f += 256) {
      float4 xv = *(const float4*)(xr + f);
      float4 wv = *(const float4*)(W + f);
      acc += xv.x * wv.x + xv.y * wv.y + xv.z * wv.z + xv.w * wv.w;
    }
    for (int off = 32; off > 0; off >>= 1) acc += __shfl_xor(acc, off, 64);
    if (lane == 0) {
      float zv = acc + b0;
      z[v] = zv;
      atomicMax(&smax[batch[v] & 1023], encf(zv));
    }
  }
  __syncthreads();
  for (int i = threadIdx.x; i < 1024; i += blockDim.x)
    if (smax[i]) atomicMax(&bmax_enc[i], smax[i]);
}

__global__ void k_e(const float* __restrict__ z, const int* __restrict__ batch,
                    const unsigned* __restrict__ bmax_enc, float* __restrict__ e,
                    float* __restrict__ bsum, int N) {
  __shared__ float ssum[1024];
  for (int i = threadIdx.x; i < 1024; i += blockDim.x) ssum[i] = 0.f;
  __syncthreads();
  int i = blockIdx.x * blockDim.x + threadIdx.x;
  if (i < N) {
    int bt = batch[i] & 1023;
    float ev = expf(z[i] - decf(bmax_enc[bt]));
    e[i] = ev;
    atomicAdd(&ssum[bt], ev);
  }
  __syncthreads();
  for (int t = threadIdx.x; t < 1024; t += blockDim.x)
    if (ssum[t] != 0.f) atomicAdd(&bsum[t], ssum[t]);
}

__global__ void k_elev(const float* __restrict__ e, const int* __restrict__ batch,
                       const float* __restrict__ bsum, float* __restrict__ elev_out, int N) {
  int i = blockIdx.x * blockDim.x + threadIdx.x;
  if (i < N) elev_out[i] = e[i] / bsum[batch[i] & 1023];
}

// per directed edge: notpeak[dst] if z[dst] < z[src]; count descending out-edges of src
__global__ void k_edges(const int* __restrict__ ei, const float* __restrict__ z,
                        int* __restrict__ notpeak, int* __restrict__ desc_cnt, int E) {
  int i = blockIdx.x * blockDim.x + threadIdx.x;
  if (i >= E) return;
  int s = ei[i], d = ei[E + i];
  float zs = z[s], zd = z[d];
  if (zd < zs) notpeak[d] = 1;
  if (zd <= zs) atomicAdd(&desc_cnt[s], 1);
}

// ---- generic chunked exclusive scan (chunk = 512, nchunks <= 1024) ----
__global__ void k_chunksum(const int* __restrict__ vals, int mode, int n,
                           int* __restrict__ chunksum) {
  __shared__ int s[512];
  int t = threadIdx.x;
  int i = blockIdx.x * 512 + t;
  int v = 0;
  if (i < n) { int a = vals[i]; v = mode ? (a == 0 ? 1 : 0) : a; }
  s[t] = v;
  __syncthreads();
  for (int off = 256; off > 0; off >>= 1) {
    if (t < off) s[t] += s[t + off];
    __syncthreads();
  }
  if (t == 0) chunksum[blockIdx.x] = s[0];
}

__global__ void k_chunkscan(int* __restrict__ chunksum, int nchunks) {
  __shared__ int s[1024];
  int t = threadIdx.x;
  int v = (t < nchunks) ? chunksum[t] : 0;
  s[t] = v;
  __syncthreads();
  for (int off = 1; off < 1024; off <<= 1) {
    int add = (t >= off) ? s[t - off] : 0;
    __syncthreads();
    s[t] += add;
    __syncthreads();
  }
  if (t < nchunks) chunksum[t] = s[t] - v;  // exclusive
}

__global__ void k_offsets(const int* __restrict__ vals, const int* __restrict__ chunkoff,
                          int* __restrict__ offs, int* __restrict__ cursor, int n) {
  __shared__ int s[512];
  int t = threadIdx.x;
  int i = blockIdx.x * 512 + t;
  int v = (i < n) ? vals[i] : 0;
  s[t] = v;
  __syncthreads();
  for (int off = 1; off < 512; off <<= 1) {
    int add = (t >= off) ? s[t - off] : 0;
    __syncthreads();
    s[t] += add;
    __syncthreads();
  }
  if (i < n) {
    int excl = s[t] - v + chunkoff[blockIdx.x];
    offs[i] = excl;
    cursor[i] = excl;
  }
}

// peak ranks -> peaklist, cbatch, out_cb, melev(=elev of peak)
__global__ void k_peak_emit(const int* __restrict__ notpeak, const int* __restrict__ chunkoff,
                            const int* __restrict__ batch, const float* __restrict__ elev,
                            int* __restrict__ peaklist, int* __restrict__ cbatch,
                            float* __restrict__ out_cb, float* __restrict__ melev,
                            int n, int P) {
  __shared__ int s[512];
  int t = threadIdx.x;
  int i = blockIdx.x * 512 + t;
  int v = (i < n) ? (notpeak[i] == 0 ? 1 : 0) : 0;
  s[t] = v;
  __syncthreads();
  for (int off = 1; off < 512; off <<= 1) {
    int add = (t >= off) ? s[t - off] : 0;
    __syncthreads();
    s[t] += add;
    __syncthreads();
  }
  if (i < n && v) {
    int r = s[t] - 1 + chunkoff[blockIdx.x];
    if (r < P) {
      peaklist[r] = i;
      int bt = batch[i];
      cbatch[r] = bt;
      out_cb[r] = (float)bt;
      melev[r] = elev[i];
    }
  }
}

__global__ void k_fill(const int* __restrict__ ei, const float* __restrict__ z,
                       int* __restrict__ cursor, int* __restrict__ adj, int E) {
  int i = blockIdx.x * blockDim.x + threadIdx.x;
  if (i >= E) return;
  int s = ei[i], d = ei[E + i];
  if (z[d] <= z[s]) {
    int pos = atomicAdd(&cursor[s], 1);
    adj[pos] = d;
  }
}

// Frontier-queue BFS per batch (one workgroup per batch, lvl in LDS, queue in
// global lnodes slice => level-sorted node list), early-exit at true depth,
// then block-local DP for deep levels [LSPLIT, depth).
__global__ void __launch_bounds__(1024, 1)
k_levels_dp(const int* __restrict__ adj, const int* __restrict__ offs,
            const int* __restrict__ cnt, const int* __restrict__ notpeak,
            int* __restrict__ level, int* __restrict__ lnodes,
            int* __restrict__ qend_g, const float* __restrict__ x,
            unsigned short* __restrict__ M, int Ng, int C) {
  extern __shared__ int lvl[];   // Ng ints
  __shared__ int s_qe, s_Lmax;
  __shared__ int qend_s[64];
  const int b = blockIdx.x, base = b * Ng;
  const int tid = threadIdx.x, nth = blockDim.x;
  int* lq = lnodes + base;       // local-id queue for this batch

  if (tid == 0) s_qe = 0;
  __syncthreads();
  for (int i = tid; i < Ng; i += nth) {
    bool pk = (notpeak[base + i] == 0);
    lvl[i] = pk ? 0 : LINF;
    if (pk) { int p = atomicAdd(&s_qe, 1); lq[p] = i; }
  }
  __syncthreads();
  int qb = 0, qe = s_qe;
  int L = 0;
  while (L < MAXL && qe > qb) {
    if (tid == 0) qend_s[L] = qe;
    for (int qi = qb + tid; qi < qe; qi += nth) {
      int u = base + lq[qi];
      int o = offs[u], oc = cnt[u];
      for (int j = 0; j < oc; ++j) {
        int wl = adj[o + j] - base;
        if (lvl[wl] == LINF) {
          int old = atomicMin(&lvl[wl], L + 1);
          if (old == LINF) { int p = atomicAdd(&s_qe, 1); lq[p] = wl; }
        }
      }
    }
    __syncthreads();
    int nq = s_qe;
    __syncthreads();
    qb = qe; qe = nq; ++L;
  }
  if (tid == 0) {
    s_Lmax = L;
    for (int l = L; l < 64; ++l) qend_s[l] = qe;
    if (L == 0) qend_s[0] = qe;
  }
  __syncthreads();
  if (tid < 64) qend_g[b * 64 + tid] = qend_s[tid];
  for (int i = tid; i < Ng; i += nth) level[base + i] = lvl[i];
  __syncthreads();
  // ---- block-local DP for deep levels: L = Lmax-1 .. LSPLIT ----
  const int lane = tid & 63, wid = tid >> 6, nwv = nth >> 6;
  const int Lmax = s_Lmax;
  for (int L2 = Lmax - 1; L2 >= LSPLIT; --L2) {
    int s = (L2 ? qend_s[L2 - 1] : 0), e = qend_s[L2];
    for (int p = s + wid; p < e; p += nwv) {
      int u = base + lq[p];
      float4 acc = ((const float4*)(x + (size_t)u * C))[lane];
      int o = offs[u], oc = cnt[u];
      for (int j = 0; j < oc; ++j) {
        int wn = adj[o + j];
        if (lvl[wn - base] == L2 + 1) {
          uint2 q = ((const uint2*)(M + (size_t)wn * C))[lane];
          acc.x = fmaxf(acc.x, bf2f(q.x & 0xffffu));
          acc.y = fmaxf(acc.y, bf2f(q.x >> 16));
          acc.z = fmaxf(acc.z, bf2f(q.y & 0xffffu));
          acc.w = fmaxf(acc.w, bf2f(q.y >> 16));
        }
      }
      uint2 pk2;
      pk2.x = f2bf(acc.x) | (f2bf(acc.y) << 16);
      pk2.y = f2bf(acc.z) | (f2bf(acc.w) << 16);
      ((uint2*)(M + (size_t)u * C))[lane] = pk2;
    }
    __syncthreads();
  }
}

// Fat-level DP: HALF-WAVE (32 lanes) per node u at level L.
//   M[u] = max(x[u], max over desc edges u->w with level[w]==L+1 of M[w])
// M rows load/store as uint4 (16 B/lane); x rows as 2x float4.
__global__ void __launch_bounds__(256, 8)
k_dp(const int* __restrict__ lnodes, const int* __restrict__ qend,
     const int* __restrict__ level, const int* __restrict__ adj,
     const int* __restrict__ offs, const int* __restrict__ cnt,
     const float* __restrict__ x, unsigned short* __restrict__ M,
     int L, int C, int Ng, int B) {
  int lane = threadIdx.x & 31;
  int ghw = (blockIdx.x * blockDim.x + threadIdx.x) >> 5;
  int nhw = (gridDim.x * blockDim.x) >> 5;
  for (int b = 0; b < B; ++b) {
    int s = L ? qend[b * 64 + L - 1] : 0;
    int e = qend[b * 64 + L];
    for (int idx = s + ghw; idx < e; idx += nhw) {
      int u = b * Ng + lnodes[b * Ng + idx];
      const float4* xr = (const float4*)(x + (size_t)u * C);
      float4 a0 = xr[2 * lane], a1 = xr[2 * lane + 1];
      int o = offs[u], oc = cnt[u];
      for (int j = 0; j < oc; j += 4) {
        int m = min(4, oc - j);
        int wn[4], lv[4];
        #pragma unroll
        for (int k = 0; k < 4; k++) wn[k] = (k < m) ? adj[o + j + k] : 0;
        #pragma unroll
        for (int k = 0; k < 4; k++) lv[k] = (k < m) ? level[wn[k]] : -1;
        uint4 q[4];
        bool use[4];
        #pragma unroll
        for (int k = 0; k < 4; k++) {
          use[k] = (lv[k] == L + 1);
          if (use[k]) q[k] = ((const uint4*)(M + (size_t)wn[k] * C))[lane];
        }
        #pragma unroll
        for (int k = 0; k < 4; k++) {
          if (use[k]) {
            a0.x = fmaxf(a0.x, bf2f(q[k].x & 0xffffu));
            a0.y = fmaxf(a0.y, bf2f(q[k].x >> 16));
            a0.z = fmaxf(a0.z, bf2f(q[k].y & 0xffffu));
            a0.w = fmaxf(a0.w, bf2f(q[k].y >> 16));
            a1.x = fmaxf(a1.x, bf2f(q[k].z & 0xffffu));
            a1.y = fmaxf(a1.y, bf2f(q[k].z >> 16));
            a1.z = fmaxf(a1.z, bf2f(q[k].w & 0xffffu));
            a1.w = fmaxf(a1.w, bf2f(q[k].w >> 16));
          }
        }
      }
      uint4 p;
      p.x = f2bf(a0.x) | (f2bf(a0.y) << 16);
      p.y = f2bf(a0.z) | (f2bf(a0.w) << 16);
      p.z = f2bf(a1.x) | (f2bf(a1.y) << 16);
      p.w = f2bf(a1.z) | (f2bf(a1.w) << 16);
      ((uint4*)(M + (size_t)u * C))[lane] = p;
    }
  }
}

// single-block cluster softmax over batches
__global__ void k_cnorm(const float* __restrict__ melev, const int* __restrict__ cbatch,
                        float* __restrict__ normed, int P) {
  __shared__ unsigned cm[1024];
  __shared__ float cs[1024];
  int t = threadIdx.x;
  for (int i = t; i < 1024; i += blockDim.x) { cm[i] = 0u; cs[i] = 0.f; }
  __syncthreads();
  for (int i = t; i < P; i += blockDim.x) atomicMax(&cm[cbatch[i] & 1023], encf(melev[i]));
  __syncthreads();
  for (int i = t; i < P; i += blockDim.x) {
    int bt = cbatch[i] & 1023;
    atomicAdd(&cs[bt], expf(melev[i] - decf(cm[bt])));
  }
  __syncthreads();
  for (int i = t; i < P; i += blockDim.x) {
    int bt = cbatch[i] & 1023;
    normed[i] = expf(melev[i] - decf(cm[bt])) / cs[bt];
  }
}

// wave per cluster: pooled[r,:] = M[peak_r,:] * normed[r]
__global__ void k_outpool(const int* __restrict__ peaklist, const float* __restrict__ normed,
                          const unsigned short* __restrict__ M, float* __restrict__ out,
                          int P, int C) {
  int lane = threadIdx.x & 63;
  int gw = (blockIdx.x * blockDim.x + threadIdx.x) >> 6;
  int nw = (gridDim.x * blockDim.x) >> 6;
  for (int r = gw; r < P; r += nw) {
    int u = peaklist[r];
    float nr = normed[r];
    uint2 q = ((const uint2*)(M + (size_t)u * C))[lane];
    float4 m;
    m.x = bf2f(q.x & 0xffffu) * nr;
    m.y = bf2f(q.x >> 16) * nr;
    m.z = bf2f(q.y & 0xffffu) * nr;
    m.w = bf2f(q.y >> 16) * nr;
    ((float4*)(out + (size_t)r * C))[lane] = m;
  }
}

extern "C" void kernel_launch(void* const* d_in, const int* in_sizes, int n_in,
                              void* d_out, int out_size, void* d_ws, size_t ws_size,
                              hipStream_t stream) {
  const float* x = (const float*)d_in[0];
  const int* ei = (const int*)d_in[1];
  const int* batch = (const int*)d_in[2];
  const float* W = (const float*)d_in[3];
  const float* b = (const float*)d_in[4];

  const int N = in_sizes[2];
  const int C = in_sizes[0] / N;
  const int E = in_sizes[1] / 2;
  const int P = (out_size - N) / (C + 1);
  const int B = 8;               // batches (setup: batch = repeat(arange(8)))
  const int Ng = N / B;          // contiguous nodes per batch

  float* out = (float*)d_out;
  float* out_pooled = out;                    // P*C
  float* out_cb = out + (size_t)P * C;        // P
  float* out_elev = out_cb + P;               // N

  // ---- workspace carve-up ----
  char* w = (char*)d_ws;
  size_t off = 0;
  auto alloc = [&](size_t bytes) -> void* {
    off = (off + 255) & ~(size_t)255;
    void* p = (void*)(w + off);
    off += bytes;
    return p;
  };
  // zero-init group (one memset covers [zero_begin, zero_end))
  size_t zero_begin = 0;
  int* notpeak      = (int*)alloc((size_t)N * 4);
  int* desc_cnt     = (int*)alloc((size_t)N * 4);
  unsigned* bmax    = (unsigned*)alloc(1024 * 4);
  float* bsum       = (float*)alloc(1024 * 4);
  size_t zero_end = off;
  // uninitialized scratch
  float* z          = (float*)alloc((size_t)N * 4);
  float* e          = (float*)alloc((size_t)N * 4);
  int* desc_off     = (int*)alloc((size_t)N * 4);
  int* cursor       = (int*)alloc((size_t)N * 4);
  int* level        = (int*)alloc((size_t)N * 4);
  int* lnodes       = (int*)alloc((size_t)N * 4);
  int* qend         = (int*)alloc((size_t)B * 64 * 4);
  const int nchunks = (N + 511) / 512;
  int* chunksum     = (int*)alloc((size_t)nchunks * 4);
  int* cbatch       = (int*)alloc((size_t)P * 4);
  float* normed     = (float*)alloc((size_t)P * 4);
  float* melev      = (float*)alloc((size_t)P * 4);
  int* peaklist     = (int*)alloc((size_t)P * 4);
  int* adj          = (int*)alloc((size_t)E * 4);
  unsigned short* M = (unsigned short*)alloc((size_t)N * C * 2);   // ~51 MB bf16

  // ---- per-call inits (ws is re-poisoned 0xAA before every launch) ----
  hipMemsetAsync(w + zero_begin, 0, zero_end - zero_begin, stream);

  // ---- z + batch max ----
  k_z<<<512, 256, 0, stream>>>(x, W, b, batch, z, bmax, N, C);
  // ---- exp + batch sum ----
  int nblkN = (N + 255) / 256;
  k_e<<<nblkN, 256, 0, stream>>>(z, batch, bmax, e, bsum, N);
  // ---- elev -> d_out ----
  k_elev<<<nblkN, 256, 0, stream>>>(e, batch, bsum, out_elev, N);
  // ---- peaks + descending degree ----
  int nblkE = (E + 255) / 256;
  k_edges<<<nblkE, 256, 0, stream>>>(ei, z, notpeak, desc_cnt, E);
  // ---- CSR offsets for descending adjacency ----
  k_chunksum<<<nchunks, 512, 0, stream>>>(desc_cnt, 0, N, chunksum);
  k_chunkscan<<<1, 1024, 0, stream>>>(chunksum, nchunks);
  k_offsets<<<nchunks, 512, 0, stream>>>(desc_cnt, chunksum, desc_off, cursor, N);
  k_fill<<<nblkE, 256, 0, stream>>>(ei, z, cursor, adj, E);
  // ---- peak ranks -> peaklist/cbatch/out_cb/melev ----
  k_chunksum<<<nchunks, 512, 0, stream>>>(notpeak, 1, N, chunksum);
  k_chunkscan<<<1, 1024, 0, stream>>>(chunksum, nchunks);
  k_peak_emit<<<nchunks, 512, 0, stream>>>(notpeak, chunksum, batch, out_elev,
                                           peaklist, cbatch, out_cb, melev, N, P);
  // ---- frontier-queue BFS levels + deep-tail DP (fused, per-batch blocks) ----
  k_levels_dp<<<B, 1024, (size_t)Ng * 4, stream>>>(adj, desc_off, desc_cnt, notpeak,
                                                   level, lnodes, qend, x, M, Ng, C);
  // ---- fat-level DP: L = LSPLIT-1 .. 0, whole machine ----
  for (int L = LSPLIT - 1; L >= 0; --L) {
    k_dp<<<2048, 256, 0, stream>>>(lnodes, qend, level, adj, desc_off, desc_cnt,
                                   x, M, L, C, Ng, B);
  }
  // ---- cluster softmax over melev (= elev of peak) ----
  k_cnorm<<<1, 1024, 0, stream>>>(melev, cbatch, normed, P);
  // ---- pooled output: gather M at peaks ----
  k_outpool<<<256, 256, 0, stream>>>(peaklist, normed, M, out_pooled, P, C);
}

// Round 9
// 628.236 us; speedup vs baseline: 1.3379x; 1.3379x over previous
//
#include <hip/hip_runtime.h>
#include <hip/hip_bf16.h>
#include <stdint.h>

// ---------------------------------------------------------------------------
// TopoPool via leveled-DAG DP (no pair frontier):
//   z = x@W.T + b ; seg-softmax elev ; peaks (no higher in-neighbor) ;
//   level[v] = BFS depth from peaks along descending edges (per-batch) ;
//   M[u] = max(x[u], max_{u->w desc, level[w]=level[u]+1} M[w])  (bottom-up) ;
//   max_x[c] = M[peak_c] ; max_elev[c] = elev[peak_c] ;
//   pooled = M[peak] * seg-softmax(elev[peak]).
// R8 post-mortem: in-kernel batch loop serialized 8 batches onto the same
//   low half-wave indices -> 8x parallelism loss. R9: batch = blockIdx.y
//   (all 8 batch segments concurrent), no VGPR clamp, 8-edge prefetch.
// ---------------------------------------------------------------------------

#define LINF 0x3FFFFFFF
#define MAXL 60
#define LSPLIT 10

__device__ __forceinline__ unsigned encf(float f) {
  unsigned u = __float_as_uint(f);
  return (u & 0x80000000u) ? ~u : (u | 0x80000000u);
}
__device__ __forceinline__ float decf(unsigned u) {
  unsigned v = (u & 0x80000000u) ? (u & 0x7fffffffu) : ~u;
  return __uint_as_float(v);
}
__device__ __forceinline__ float bf2f(unsigned h) {
  return __uint_as_float(h << 16);
}
__device__ __forceinline__ unsigned f2bf(float f) {
  unsigned u = __float_as_uint(f);
  return (u + 0x7FFFu + ((u >> 16) & 1u)) >> 16;   // RNE
}

// wave-per-node dot(x[v], W) + b; per-block LDS batch max -> global encoded max
__global__ void k_z(const float* __restrict__ x, const float* __restrict__ W,
                    const float* __restrict__ b, const int* __restrict__ batch,
                    float* __restrict__ z, unsigned* __restrict__ bmax_enc,
                    int N, int C) {
  __shared__ unsigned smax[1024];
  for (int i = threadIdx.x; i < 1024; i += blockDim.x) smax[i] = 0u;
  __syncthreads();
  int lane = threadIdx.x & 63;
  int wid = threadIdx.x >> 6;
  int wavesPerBlock = blockDim.x >> 6;
  int gw = blockIdx.x * wavesPerBlock + wid;
  int nw = gridDim.x * wavesPerBlock;
  float b0 = b[0];
  for (int v = gw; v < N; v += nw) {
    const float* xr = x + (size_t)v * C;
    float acc = 0.f;
    for (int f = lane * 4; f < C; f += 256) {
      float4 xv = *(const float4*)(xr + f);
      float4 wv = *(const float4*)(W + f);
      acc += xv.x * wv.x + xv.y * wv.y + xv.z * wv.z + xv.w * wv.w;
    }
    for (int off = 32; off > 0; off >>= 1) acc += __shfl_xor(acc, off, 64);
    if (lane == 0) {
      float zv = acc + b0;
      z[v] = zv;
      atomicMax(&smax[batch[v] & 1023], encf(zv));
    }
  }
  __syncthreads();
  for (int i = threadIdx.x; i < 1024; i += blockDim.x)
    if (smax[i]) atomicMax(&bmax_enc[i], smax[i]);
}

__global__ void k_e(const float* __restrict__ z, const int* __restrict__ batch,
                    const unsigned* __restrict__ bmax_enc, float* __restrict__ e,
                    float* __restrict__ bsum, int N) {
  __shared__ float ssum[1024];
  for (int i = threadIdx.x; i < 1024; i += blockDim.x) ssum[i] = 0.f;
  __syncthreads();
  int i = blockIdx.x * blockDim.x + threadIdx.x;
  if (i < N) {
    int bt = batch[i] & 1023;
    float ev = expf(z[i] - decf(bmax_enc[bt]));
    e[i] = ev;
    atomicAdd(&ssum[bt], ev);
  }
  __syncthreads();
  for (int t = threadIdx.x; t < 1024; t += blockDim.x)
    if (ssum[t] != 0.f) atomicAdd(&bsum[t], ssum[t]);
}

__global__ void k_elev(const float* __restrict__ e, const int* __restrict__ batch,
                       const float* __restrict__ bsum, float* __restrict__ elev_out, int N) {
  int i = blockIdx.x * blockDim.x + threadIdx.x;
  if (i < N) elev_out[i] = e[i] / bsum[batch[i] & 1023];
}

// per directed edge: notpeak[dst] if z[dst] < z[src]; count descending out-edges of src
__global__ void k_edges(const int* __restrict__ ei, const float* __restrict__ z,
                        int* __restrict__ notpeak, int* __restrict__ desc_cnt, int E) {
  int i = blockIdx.x * blockDim.x + threadIdx.x;
  if (i >= E) return;
  int s = ei[i], d = ei[E + i];
  float zs = z[s], zd = z[d];
  if (zd < zs) notpeak[d] = 1;
  if (zd <= zs) atomicAdd(&desc_cnt[s], 1);
}

// ---- generic chunked exclusive scan (chunk = 512, nchunks <= 1024) ----
__global__ void k_chunksum(const int* __restrict__ vals, int mode, int n,
                           int* __restrict__ chunksum) {
  __shared__ int s[512];
  int t = threadIdx.x;
  int i = blockIdx.x * 512 + t;
  int v = 0;
  if (i < n) { int a = vals[i]; v = mode ? (a == 0 ? 1 : 0) : a; }
  s[t] = v;
  __syncthreads();
  for (int off = 256; off > 0; off >>= 1) {
    if (t < off) s[t] += s[t + off];
    __syncthreads();
  }
  if (t == 0) chunksum[blockIdx.x] = s[0];
}

__global__ void k_chunkscan(int* __restrict__ chunksum, int nchunks) {
  __shared__ int s[1024];
  int t = threadIdx.x;
  int v = (t < nchunks) ? chunksum[t] : 0;
  s[t] = v;
  __syncthreads();
  for (int off = 1; off < 1024; off <<= 1) {
    int add = (t >= off) ? s[t - off] : 0;
    __syncthreads();
    s[t] += add;
    __syncthreads();
  }
  if (t < nchunks) chunksum[t] = s[t] - v;  // exclusive
}

__global__ void k_offsets(const int* __restrict__ vals, const int* __restrict__ chunkoff,
                          int* __restrict__ offs, int* __restrict__ cursor, int n) {
  __shared__ int s[512];
  int t = threadIdx.x;
  int i = blockIdx.x * 512 + t;
  int v = (i < n) ? vals[i] : 0;
  s[t] = v;
  __syncthreads();
  for (int off = 1; off < 512; off <<= 1) {
    int add = (t >= off) ? s[t - off] : 0;
    __syncthreads();
    s[t] += add;
    __syncthreads();
  }
  if (i < n) {
    int excl = s[t] - v + chunkoff[blockIdx.x];
    offs[i] = excl;
    cursor[i] = excl;
  }
}

// peak ranks -> peaklist, cbatch, out_cb, melev(=elev of peak)
__global__ void k_peak_emit(const int* __restrict__ notpeak, const int* __restrict__ chunkoff,
                            const int* __restrict__ batch, const float* __restrict__ elev,
                            int* __restrict__ peaklist, int* __restrict__ cbatch,
                            float* __restrict__ out_cb, float* __restrict__ melev,
                            int n, int P) {
  __shared__ int s[512];
  int t = threadIdx.x;
  int i = blockIdx.x * 512 + t;
  int v = (i < n) ? (notpeak[i] == 0 ? 1 : 0) : 0;
  s[t] = v;
  __syncthreads();
  for (int off = 1; off < 512; off <<= 1) {
    int add = (t >= off) ? s[t - off] : 0;
    __syncthreads();
    s[t] += add;
    __syncthreads();
  }
  if (i < n && v) {
    int r = s[t] - 1 + chunkoff[blockIdx.x];
    if (r < P) {
      peaklist[r] = i;
      int bt = batch[i];
      cbatch[r] = bt;
      out_cb[r] = (float)bt;
      melev[r] = elev[i];
    }
  }
}

__global__ void k_fill(const int* __restrict__ ei, const float* __restrict__ z,
                       int* __restrict__ cursor, int* __restrict__ adj, int E) {
  int i = blockIdx.x * blockDim.x + threadIdx.x;
  if (i >= E) return;
  int s = ei[i], d = ei[E + i];
  if (z[d] <= z[s]) {
    int pos = atomicAdd(&cursor[s], 1);
    adj[pos] = d;
  }
}

// Frontier-queue BFS per batch (one workgroup per batch, lvl in LDS, queue in
// global lnodes slice => level-sorted node list), early-exit at true depth,
// then block-local DP for deep levels [LSPLIT, depth).
__global__ void __launch_bounds__(1024, 1)
k_levels_dp(const int* __restrict__ adj, const int* __restrict__ offs,
            const int* __restrict__ cnt, const int* __restrict__ notpeak,
            int* __restrict__ level, int* __restrict__ lnodes,
            int* __restrict__ qend_g, const float* __restrict__ x,
            unsigned short* __restrict__ M, int Ng, int C) {
  extern __shared__ int lvl[];   // Ng ints
  __shared__ int s_qe, s_Lmax;
  __shared__ int qend_s[64];
  const int b = blockIdx.x, base = b * Ng;
  const int tid = threadIdx.x, nth = blockDim.x;
  int* lq = lnodes + base;       // local-id queue for this batch

  if (tid == 0) s_qe = 0;
  __syncthreads();
  for (int i = tid; i < Ng; i += nth) {
    bool pk = (notpeak[base + i] == 0);
    lvl[i] = pk ? 0 : LINF;
    if (pk) { int p = atomicAdd(&s_qe, 1); lq[p] = i; }
  }
  __syncthreads();
  int qb = 0, qe = s_qe;
  int L = 0;
  while (L < MAXL && qe > qb) {
    if (tid == 0) qend_s[L] = qe;
    for (int qi = qb + tid; qi < qe; qi += nth) {
      int u = base + lq[qi];
      int o = offs[u], oc = cnt[u];
      for (int j = 0; j < oc; ++j) {
        int wl = adj[o + j] - base;
        if (lvl[wl] == LINF) {
          int old = atomicMin(&lvl[wl], L + 1);
          if (old == LINF) { int p = atomicAdd(&s_qe, 1); lq[p] = wl; }
        }
      }
    }
    __syncthreads();
    int nq = s_qe;
    __syncthreads();
    qb = qe; qe = nq; ++L;
  }
  if (tid == 0) {
    s_Lmax = L;
    for (int l = L; l < 64; ++l) qend_s[l] = qe;
    if (L == 0) qend_s[0] = qe;
  }
  __syncthreads();
  if (tid < 64) qend_g[b * 64 + tid] = qend_s[tid];
  for (int i = tid; i < Ng; i += nth) level[base + i] = lvl[i];
  __syncthreads();
  // ---- block-local DP for deep levels: L = Lmax-1 .. LSPLIT ----
  const int lane = tid & 63, wid = tid >> 6, nwv = nth >> 6;
  const int Lmax = s_Lmax;
  for (int L2 = Lmax - 1; L2 >= LSPLIT; --L2) {
    int s = (L2 ? qend_s[L2 - 1] : 0), e = qend_s[L2];
    for (int p = s + wid; p < e; p += nwv) {
      int u = base + lq[p];
      float4 acc = ((const float4*)(x + (size_t)u * C))[lane];
      int o = offs[u], oc = cnt[u];
      for (int j = 0; j < oc; ++j) {
        int wn = adj[o + j];
        if (lvl[wn - base] == L2 + 1) {
          uint2 q = ((const uint2*)(M + (size_t)wn * C))[lane];
          acc.x = fmaxf(acc.x, bf2f(q.x & 0xffffu));
          acc.y = fmaxf(acc.y, bf2f(q.x >> 16));
          acc.z = fmaxf(acc.z, bf2f(q.y & 0xffffu));
          acc.w = fmaxf(acc.w, bf2f(q.y >> 16));
        }
      }
      uint2 pk2;
      pk2.x = f2bf(acc.x) | (f2bf(acc.y) << 16);
      pk2.y = f2bf(acc.z) | (f2bf(acc.w) << 16);
      ((uint2*)(M + (size_t)u * C))[lane] = pk2;
    }
    __syncthreads();
  }
}

// Fat-level DP: HALF-WAVE (32 lanes) per node u at level L; batch = blockIdx.y
// so all 8 batch segments run concurrently (R8 had them serialized onto the
// same low half-wave indices).
//   M[u] = max(x[u], max over desc edges u->w with level[w]==L+1 of M[w])
// M rows load/store as uint4 (16 B/lane); x rows as 2x float4.
__global__ void __launch_bounds__(256)
k_dp(const int* __restrict__ lnodes, const int* __restrict__ qend,
     const int* __restrict__ level, const int* __restrict__ adj,
     const int* __restrict__ offs, const int* __restrict__ cnt,
     const float* __restrict__ x, unsigned short* __restrict__ M,
     int L, int C, int Ng) {
  const int b = blockIdx.y;
  int lane = threadIdx.x & 31;
  int ghw = (blockIdx.x * blockDim.x + threadIdx.x) >> 5;
  int nhw = (gridDim.x * blockDim.x) >> 5;
  int s = L ? qend[b * 64 + L - 1] : 0;
  int e = qend[b * 64 + L];
  for (int idx = s + ghw; idx < e; idx += nhw) {
    int u = b * Ng + lnodes[b * Ng + idx];
    const float4* xr = (const float4*)(x + (size_t)u * C);
    float4 a0 = xr[2 * lane], a1 = xr[2 * lane + 1];
    int o = offs[u], oc = cnt[u];
    for (int j = 0; j < oc; j += 8) {
      int m = min(8, oc - j);
      int wn[8], lv[8];
      #pragma unroll
      for (int k = 0; k < 8; k++) wn[k] = (k < m) ? adj[o + j + k] : 0;
      #pragma unroll
      for (int k = 0; k < 8; k++) lv[k] = (k < m) ? level[wn[k]] : -1;
      #pragma unroll
      for (int k = 0; k < 8; k++) {
        if (lv[k] == L + 1) {
          uint4 q = ((const uint4*)(M + (size_t)wn[k] * C))[lane];
          a0.x = fmaxf(a0.x, bf2f(q.x & 0xffffu));
          a0.y = fmaxf(a0.y, bf2f(q.x >> 16));
          a0.z = fmaxf(a0.z, bf2f(q.y & 0xffffu));
          a0.w = fmaxf(a0.w, bf2f(q.y >> 16));
          a1.x = fmaxf(a1.x, bf2f(q.z & 0xffffu));
          a1.y = fmaxf(a1.y, bf2f(q.z >> 16));
          a1.z = fmaxf(a1.z, bf2f(q.w & 0xffffu));
          a1.w = fmaxf(a1.w, bf2f(q.w >> 16));
        }
      }
    }
    uint4 p;
    p.x = f2bf(a0.x) | (f2bf(a0.y) << 16);
    p.y = f2bf(a0.z) | (f2bf(a0.w) << 16);
    p.z = f2bf(a1.x) | (f2bf(a1.y) << 16);
    p.w = f2bf(a1.z) | (f2bf(a1.w) << 16);
    ((uint4*)(M + (size_t)u * C))[lane] = p;
  }
}

// single-block cluster softmax over batches
__global__ void k_cnorm(const float* __restrict__ melev, const int* __restrict__ cbatch,
                        float* __restrict__ normed, int P) {
  __shared__ unsigned cm[1024];
  __shared__ float cs[1024];
  int t = threadIdx.x;
  for (int i = t; i < 1024; i += blockDim.x) { cm[i] = 0u; cs[i] = 0.f; }
  __syncthreads();
  for (int i = t; i < P; i += blockDim.x) atomicMax(&cm[cbatch[i] & 1023], encf(melev[i]));
  __syncthreads();
  for (int i = t; i < P; i += blockDim.x) {
    int bt = cbatch[i] & 1023;
    atomicAdd(&cs[bt], expf(melev[i] - decf(cm[bt])));
  }
  __syncthreads();
  for (int i = t; i < P; i += blockDim.x) {
    int bt = cbatch[i] & 1023;
    normed[i] = expf(melev[i] - decf(cm[bt])) / cs[bt];
  }
}

// wave per cluster: pooled[r,:] = M[peak_r,:] * normed[r]
__global__ void k_outpool(const int* __restrict__ peaklist, const float* __restrict__ normed,
                          const unsigned short* __restrict__ M, float* __restrict__ out,
                          int P, int C) {
  int lane = threadIdx.x & 63;
  int gw = (blockIdx.x * blockDim.x + threadIdx.x) >> 6;
  int nw = (gridDim.x * blockDim.x) >> 6;
  for (int r = gw; r < P; r += nw) {
    int u = peaklist[r];
    float nr = normed[r];
    uint2 q = ((const uint2*)(M + (size_t)u * C))[lane];
    float4 m;
    m.x = bf2f(q.x & 0xffffu) * nr;
    m.y = bf2f(q.x >> 16) * nr;
    m.z = bf2f(q.y & 0xffffu) * nr;
    m.w = bf2f(q.y >> 16) * nr;
    ((float4*)(out + (size_t)r * C))[lane] = m;
  }
}

extern "C" void kernel_launch(void* const* d_in, const int* in_sizes, int n_in,
                              void* d_out, int out_size, void* d_ws, size_t ws_size,
                              hipStream_t stream) {
  const float* x = (const float*)d_in[0];
  const int* ei = (const int*)d_in[1];
  const int* batch = (const int*)d_in[2];
  const float* W = (const float*)d_in[3];
  const float* b = (const float*)d_in[4];

  const int N = in_sizes[2];
  const int C = in_sizes[0] / N;
  const int E = in_sizes[1] / 2;
  const int P = (out_size - N) / (C + 1);
  const int B = 8;               // batches (setup: batch = repeat(arange(8)))
  const int Ng = N / B;          // contiguous nodes per batch

  float* out = (float*)d_out;
  float* out_pooled = out;                    // P*C
  float* out_cb = out + (size_t)P * C;        // P
  float* out_elev = out_cb + P;               // N

  // ---- workspace carve-up ----
  char* w = (char*)d_ws;
  size_t off = 0;
  auto alloc = [&](size_t bytes) -> void* {
    off = (off + 255) & ~(size_t)255;
    void* p = (void*)(w + off);
    off += bytes;
    return p;
  };
  // zero-init group (one memset covers [zero_begin, zero_end))
  size_t zero_begin = 0;
  int* notpeak      = (int*)alloc((size_t)N * 4);
  int* desc_cnt     = (int*)alloc((size_t)N * 4);
  unsigned* bmax    = (unsigned*)alloc(1024 * 4);
  float* bsum       = (float*)alloc(1024 * 4);
  size_t zero_end = off;
  // uninitialized scratch
  float* z          = (float*)alloc((size_t)N * 4);
  float* e          = (float*)alloc((size_t)N * 4);
  int* desc_off     = (int*)alloc((size_t)N * 4);
  int* cursor       = (int*)alloc((size_t)N * 4);
  int* level        = (int*)alloc((size_t)N * 4);
  int* lnodes       = (int*)alloc((size_t)N * 4);
  int* qend         = (int*)alloc((size_t)B * 64 * 4);
  const int nchunks = (N + 511) / 512;
  int* chunksum     = (int*)alloc((size_t)nchunks * 4);
  int* cbatch       = (int*)alloc((size_t)P * 4);
  float* normed     = (float*)alloc((size_t)P * 4);
  float* melev      = (float*)alloc((size_t)P * 4);
  int* peaklist     = (int*)alloc((size_t)P * 4);
  int* adj          = (int*)alloc((size_t)E * 4);
  unsigned short* M = (unsigned short*)alloc((size_t)N * C * 2);   // ~51 MB bf16

  // ---- per-call inits (ws is re-poisoned 0xAA before every launch) ----
  hipMemsetAsync(w + zero_begin, 0, zero_end - zero_begin, stream);

  // ---- z + batch max ----
  k_z<<<512, 256, 0, stream>>>(x, W, b, batch, z, bmax, N, C);
  // ---- exp + batch sum ----
  int nblkN = (N + 255) / 256;
  k_e<<<nblkN, 256, 0, stream>>>(z, batch, bmax, e, bsum, N);
  // ---- elev -> d_out ----
  k_elev<<<nblkN, 256, 0, stream>>>(e, batch, bsum, out_elev, N);
  // ---- peaks + descending degree ----
  int nblkE = (E + 255) / 256;
  k_edges<<<nblkE, 256, 0, stream>>>(ei, z, notpeak, desc_cnt, E);
  // ---- CSR offsets for descending adjacency ----
  k_chunksum<<<nchunks, 512, 0, stream>>>(desc_cnt, 0, N, chunksum);
  k_chunkscan<<<1, 1024, 0, stream>>>(chunksum, nchunks);
  k_offsets<<<nchunks, 512, 0, stream>>>(desc_cnt, chunksum, desc_off, cursor, N);
  k_fill<<<nblkE, 256, 0, stream>>>(ei, z, cursor, adj, E);
  // ---- peak ranks -> peaklist/cbatch/out_cb/melev ----
  k_chunksum<<<nchunks, 512, 0, stream>>>(notpeak, 1, N, chunksum);
  k_chunkscan<<<1, 1024, 0, stream>>>(chunksum, nchunks);
  k_peak_emit<<<nchunks, 512, 0, stream>>>(notpeak, chunksum, batch, out_elev,
                                           peaklist, cbatch, out_cb, melev, N, P);
  // ---- frontier-queue BFS levels + deep-tail DP (fused, per-batch blocks) ----
  k_levels_dp<<<B, 1024, (size_t)Ng * 4, stream>>>(adj, desc_off, desc_cnt, notpeak,
                                                   level, lnodes, qend, x, M, Ng, C);
  // ---- fat-level DP: L = LSPLIT-1 .. 0, batches concurrent via blockIdx.y ----
  dim3 gdp(256, B);
  for (int L = LSPLIT - 1; L >= 0; --L) {
    k_dp<<<gdp, 256, 0, stream>>>(lnodes, qend, level, adj, desc_off, desc_cnt,
                                  x, M, L, C, Ng);
  }
  // ---- cluster softmax over melev (= elev of peak) ----
  k_cnorm<<<1, 1024, 0, stream>>>(melev, cbatch, normed, P);
  // ---- pooled output: gather M at peaks ----
  k_outpool<<<256, 256, 0, stream>>>(peaklist, normed, M, out_pooled, P, C);
}